// Round 4
// baseline (154.486 us; speedup 1.0000x reference)
//
#include <hip/hip_runtime.h>

// B=2, T=2048, D_MODEL=1024, H=16, Dh=64. Inputs fp32, output fp32.
// R15: attn inner loop rebuilt on 32x32x16 MFMA with 2x2 (q-half x k-half)
// wave grid. R14 post-mortem: LDS pipe was the bottleneck (every wave read
// the full 8KB K + 8KB V tile per chunk = 80 b128/chunk-block ~= 26us/CU).
// Now each wave reads only its half-K (QK) and half-V (PV): 32 b128/chunk
// -> ~10.6us LDS floor. P stays in registers: swapped QK (rows=k, cols=q)
// + 8 v_cvt_pk_bf16_f32 + 4 v_permlane32_swap_b32 build the PV B-operand
// directly (no Ps buffer, no lgkm round-trip). wk-partial O/l reduced once
// per strip via padded-LDS epilogue (also fixes O^T write coalescing).
// Geometry unchanged from R14: 64q strips, 64k chunks, pairs {p,31-p},
// grid 512x256, K/V dbuf staging via global_load_lds with XOR swizzle.
// gemm/cvt unchanged.

using bf16x8   = __attribute__((ext_vector_type(8))) __bf16;
using floatx4  = __attribute__((ext_vector_type(4))) float;
using floatx16 = __attribute__((ext_vector_type(16))) float;
using uintx4   = __attribute__((ext_vector_type(4))) unsigned int;

#define T_SEQ   2048
#define D_MODEL 1024
#define N_HEADS 16
#define D_HEAD  64
#define BATCH   2
#define M_TOT   4096
#define N_TOT   3072
#define PLANE   (T_SEQ * D_HEAD)
#define NX      (M_TOT * D_MODEL)
#define NWSEG   (D_MODEL * D_MODEL)
#define QSCALE  0.18033688f   // 0.125 * log2(e)
#define SM_BIAS 24.0f

__device__ __forceinline__ unsigned short f32_to_bf16(float f) {
  unsigned int u = __float_as_uint(f);
  u += 0x7fffu + ((u >> 16) & 1u);
  return (unsigned short)(u >> 16);
}
__device__ __forceinline__ unsigned int pack2_bf16(float a, float b) {
  unsigned int ua = __float_as_uint(a) + 0x8000u;
  unsigned int ub = __float_as_uint(b) + 0x8000u;
  return __builtin_amdgcn_perm(ub, ua, 0x07060302);
}
__device__ __forceinline__ void async_cp16(void* lds, const void* gptr) {
  __builtin_amdgcn_global_load_lds(
      (const __attribute__((address_space(1))) unsigned int*)gptr,
      (__attribute__((address_space(3))) unsigned int*)lds, 16, 0, 0);
}

// ---------------------------------------------------------------------------
// K0: fp32 -> bf16 cvt.
// ---------------------------------------------------------------------------
__global__ __launch_bounds__(256) void cvt_kernel(
    const float* __restrict__ X,  const float* __restrict__ Wq,
    const float* __restrict__ Wk, const float* __restrict__ Wv,
    unsigned short* __restrict__ Xb, unsigned short* __restrict__ Wb)
{
  const size_t i = ((size_t)blockIdx.x * 256 + threadIdx.x) * 8;
  const float* src;
  unsigned short* dst;
  if (i < NX) { src = X + i; dst = Xb + i; }
  else {
    const size_t r = i - NX;
    const int w = (int)(r >> 20);
    const size_t o = r & (NWSEG - 1);
    src = ((w == 0) ? Wq : (w == 1) ? Wk : Wv) + o;
    dst = Wb + r;
  }
  float4 f0 = *(const float4*)src;
  float4 f1 = *(const float4*)(src + 4);
  uint4 out;
  out.x = pack2_bf16(f0.x, f0.y);
  out.y = pack2_bf16(f0.z, f0.w);
  out.z = pack2_bf16(f1.x, f1.y);
  out.w = pack2_bf16(f1.z, f1.w);
  *(uint4*)dst = out;
}

// ---------------------------------------------------------------------------
// K1: bf16 GEMM C[4096x3072] = Xb @ Wb^T. Grid (24,32), block 256. BK=64.
// ---------------------------------------------------------------------------
__global__ __launch_bounds__(256) void gemm_qkv(
    const unsigned short* __restrict__ Xb,
    const unsigned short* __restrict__ Wb,
    unsigned short* __restrict__ Qb,         // [B][H][T][64] * QSCALE
    unsigned short* __restrict__ Kb,         // [B][H][T][64]
    unsigned short* __restrict__ VTb)        // [B][H][64][T]
{
  __shared__ unsigned short Als[128 * 64];
  __shared__ unsigned short Bls[128 * 64];

  const int tid  = threadIdx.x;
  const int lane = tid & 63;
  const int wave = tid >> 6;
  const int l15  = lane & 15;
  const int quad = lane >> 4;
  const int wm   = wave >> 1, wn = wave & 1;

  const int n_blk = blockIdx.x * 128;
  const int m_blk = blockIdx.y * 128;

  const int swz = (((tid >> 3) ^ tid) & 7) * 8;
  const unsigned short* Ag = Xb + (size_t)(m_blk + (tid >> 3)) * D_MODEL + swz;
  const unsigned short* Bg = Wb + (size_t)(n_blk + (tid >> 3)) * D_MODEL + swz;
  char* Alds = (char*)Als + wave * 1024;
  char* Blds = (char*)Bls + wave * 1024;

  floatx4 acc[4][4] = {};

  for (int k0 = 0; k0 < D_MODEL; k0 += 64) {
    __syncthreads();
#pragma unroll
    for (int p = 0; p < 4; p++) {
      async_cp16(Alds + p * 4096, Ag + (size_t)p * 32 * D_MODEL + k0);
      async_cp16(Blds + p * 4096, Bg + (size_t)p * 32 * D_MODEL + k0);
    }
    __syncthreads();

#pragma unroll
    for (int ks = 0; ks < 2; ks++) {
      bf16x8 a[4], b[4];
#pragma unroll
      for (int i = 0; i < 4; i++) {
        const int sa = ((ks * 4 + quad) ^ (l15 & 7)) * 16;
        a[i] = *(const bf16x8*)((char*)Als + (wm * 64 + 16 * i + l15) * 128 + sa);
        b[i] = *(const bf16x8*)((char*)Bls + (wn * 64 + 16 * i + l15) * 128 + sa);
      }
#pragma unroll
      for (int mi = 0; mi < 4; mi++)
#pragma unroll
        for (int ni = 0; ni < 4; ni++)
          acc[mi][ni] = __builtin_amdgcn_mfma_f32_16x16x32_bf16(a[mi], b[ni], acc[mi][ni], 0, 0, 0);
    }
  }

  // epilogue: stage 64x64 C tile in LDS (swizzled), coalesced copy-out
  __syncthreads();
  char* ep = (char*)Als + wave * 8192;
  const int w_sel  = n_blk >> 10;
  const int m_base = m_blk + wm * 64;
  const int n_base = n_blk + wn * 64;
  const int h      = (n_base & 1023) >> 6;
  const float csc  = (w_sel == 0) ? QSCALE : 1.0f;

  if (w_sel < 2) {
#pragma unroll
    for (int mi = 0; mi < 4; mi++)
#pragma unroll
      for (int ni = 0; ni < 4; ni++)
#pragma unroll
        for (int r = 0; r < 4; r++) {
          const int row  = 16 * mi + quad * 4 + r;
          const int colb = (16 * ni + l15) * 2;
          const int phys = ((colb >> 4) ^ (row & 7)) * 16;
          *(unsigned short*)(ep + row * 128 + phys + (colb & 15)) =
              f32_to_bf16(acc[mi][ni][r] * csc);
        }
  } else {
#pragma unroll
    for (int mi = 0; mi < 4; mi++)
#pragma unroll
      for (int ni = 0; ni < 4; ni++)
#pragma unroll
        for (int r = 0; r < 4; r++) {
          const int row  = 16 * ni + l15;
          const int colb = (16 * mi + quad * 4 + r) * 2;
          const int phys = ((colb >> 4) ^ (row & 7)) * 16;
          *(unsigned short*)(ep + row * 128 + phys + (colb & 15)) =
              f32_to_bf16(acc[mi][ni][r]);
        }
  }
  asm volatile("s_waitcnt lgkmcnt(0)" ::: "memory");

#pragma unroll
  for (int pass = 0; pass < 8; pass++) {
    const int row  = pass * 8 + (lane >> 3);
    const int phys = ((lane & 7) ^ (row & 7)) * 16;
    uint4 v = *(const uint4*)(ep + row * 128 + phys);
    if (w_sel < 2) {
      const int m  = m_base + row;
      const int bb = m >> 11;
      const int t  = m & (T_SEQ - 1);
      unsigned short* dst = ((w_sel == 0) ? Qb : Kb) +
          ((size_t)(bb * N_HEADS + h) * T_SEQ + t) * D_HEAD + (lane & 7) * 8;
      *(uint4*)dst = v;
    } else {
      const int bb = m_base >> 11;
      unsigned short* dst = VTb +
          ((size_t)(bb * N_HEADS + h) * D_HEAD + row) * T_SEQ + (m_base & (T_SEQ - 1)) + (lane & 7) * 8;
      *(uint4*)dst = v;
    }
  }
}

// ---------------------------------------------------------------------------
// K2: causal flash attention, fixed-max softmax, 32x32x16 MFMA.
// Grid 512 x 256: bh = blockIdx & 31 (XCD = bh%8), pair = blockIdx >> 5.
// Block = 4 waves in a 2x2 grid: wq = q-half (32q), wk = k-half (32k).
// Strips {pair, 31-pair} sequential = 33 chunks/block for every block.
// P built in registers via cvt_pk + permlane32_swap (no LDS P buffer).
// Per-wave partial O^T/l reduced across wk once per strip via LDS epilogue.
// ---------------------------------------------------------------------------
__global__ __launch_bounds__(256) void attn_kernel(
    const unsigned short* __restrict__ Qb,   // pre-scaled by QSCALE
    const unsigned short* __restrict__ Kb,
    const unsigned short* __restrict__ VTb,
    float* __restrict__ Out)
{
  // chunk phase:    Ks dbuf [2][8192] @ 0, Vs dbuf [2][8192] @ 16384
  // epilogue phase: OB [4][64][33] f32 @ 0 (33792 B), LB [2][64] f32 @ 33792
  __shared__ __align__(16) char smem[34304];

  const int tid  = threadIdx.x;
  const int lane = tid & 63;
  const int wave = tid >> 6;
  const int l31  = lane & 31;
  const int q1   = lane >> 5;
  const int wq   = wave & 1;       // q-half
  const int wk   = wave >> 1;      // k-half

  const int bh   = blockIdx.x & 31;          // inner -> XCD affinity (bh % 8)
  const int pair = blockIdx.x >> 5;          // 0..15

  const unsigned short* Qp = Qb  + (size_t)bh * PLANE;
  const unsigned short* Kp = Kb  + (size_t)bh * PLANE;
  const unsigned short* Vp = VTb + (size_t)bh * PLANE;

  const int swz = (((tid >> 3) ^ tid) & 7) * 8;
  const unsigned short* Kg = Kp + (size_t)(tid >> 3) * D_HEAD + swz;
  const unsigned short* Vg = Vp + (size_t)(tid >> 3) * T_SEQ + swz;
  const int b = bh >> 4, h = bh & 15;

  char* const Ks0 = smem;
  char* const Ks1 = smem + 8192;
  char* const Vs0 = smem + 16384;
  char* const Vs1 = smem + 24576;
  float* const LB = (float*)(smem + 33792);

#pragma unroll 1
  for (int it = 0; it < 2; it++) {
    const int strip = it ? (31 - pair) : pair;
    const int qbase = strip * 64 + wq * 32;
    const int nch   = strip + 1;

    // Q fragments: B-operand, lane = q (l31), elems = d
    bf16x8 aq[4];
#pragma unroll
    for (int kp = 0; kp < 4; kp++)
      aq[kp] = *(const bf16x8*)(Qp + (size_t)(qbase + l31) * D_HEAD + kp * 16 + q1 * 8);

    floatx16 o0 = {}, o1 = {};
    float l_acc = 0.0f;

    // previous strip's epilogue reads must finish before re-staging
    __syncthreads();

    // prologue: stage chunk 0 -> buf 0
#pragma unroll
    for (int p = 0; p < 2; p++) {
      async_cp16(Ks0 + p * 4096 + wave * 1024, Kg + (size_t)(p * 32) * D_HEAD);
      async_cp16(Vs0 + p * 4096 + wave * 1024, Vg + (size_t)(p * 32) * T_SEQ);
    }

    for (int jc = 0; jc < nch; jc++) {
      __syncthreads();
      if (jc + 1 < nch) {
        const int j1 = (jc + 1) * 64;
        char* kd = ((jc + 1) & 1) ? Ks1 : Ks0;
        char* vd = ((jc + 1) & 1) ? Vs1 : Vs0;
#pragma unroll
        for (int p = 0; p < 2; p++) {
          async_cp16(kd + p * 4096 + wave * 1024, Kg + (size_t)(j1 + p * 32) * D_HEAD);
          async_cp16(vd + p * 4096 + wave * 1024, Vg + (size_t)(p * 32) * T_SEQ + j1);
        }
      }
      const char* Ksb = (jc & 1) ? Ks1 : Ks0;
      const char* Vsb = (jc & 1) ? Vs1 : Vs0;
      const int kbase = jc * 64 + wk * 32;

      if (kbase <= qbase + 31) {          // wave's k-half not fully masked
        // S^T = K Q^T: rows = k (l31 within half-tile), cols = q
        floatx16 s = {};
        const int krow = wk * 32 + l31;
#pragma unroll
        for (int kp = 0; kp < 4; kp++) {
          const int phys = (((2 * kp + q1) ^ (krow & 7)) * 16);
          bf16x8 ak = *(const bf16x8*)(Ksb + krow * 128 + phys);
          s = __builtin_amdgcn_mfma_f32_32x32x16_bf16(ak, aq[kp], s, 0, 0, 0);
        }

        if (kbase >= qbase) {             // diagonal tile: mask k > q
          const int q = qbase + l31;
#pragma unroll
          for (int r = 0; r < 16; r++) {
            const int kk = kbase + (r & 3) + 8 * (r >> 2) + 4 * q1;
            if (kk > q) s[r] = -INFINITY;
          }
        }

        // fixed-bias softmax: p = exp2(s - SM_BIAS)
        float pv[16];
#pragma unroll
        for (int r = 0; r < 16; r++)
          pv[r] = __builtin_amdgcn_exp2f(s[r] - SM_BIAS);
#pragma unroll
        for (int r = 0; r < 16; r += 4)
          l_acc += (pv[r] + pv[r + 1]) + (pv[r + 2] + pv[r + 3]);

        // pack to bf16 pairs (consecutive k)
        unsigned int w[8];
#pragma unroll
        for (int m = 0; m < 8; m++)
          asm("v_cvt_pk_bf16_f32 %0, %1, %2" : "=v"(w[m]) : "v"(pv[2 * m]), "v"(pv[2 * m + 1]));

        // build PV B-operand fragments via permlane32_swap, then PV
#pragma unroll
        for (int kp = 0; kp < 2; kp++) {
          unsigned int b0 = w[4 * kp],     b2 = w[4 * kp + 2];
          unsigned int b1 = w[4 * kp + 1], b3 = w[4 * kp + 3];
          asm("v_permlane32_swap_b32 %0, %1" : "+v"(b0), "+v"(b2));
          asm("v_permlane32_swap_b32 %0, %1" : "+v"(b1), "+v"(b3));
          uintx4 u; u[0] = b0; u[1] = b1; u[2] = b2; u[3] = b3;
          const bf16x8 pf = __builtin_bit_cast(bf16x8, u);

          const int c = 4 * wk + 2 * kp + q1;   // key 16B-chunk in V rows
          const int row0 = l31;
          bf16x8 av0 = *(const bf16x8*)(Vsb + row0 * 128 + ((c ^ (row0 & 7)) * 16));
          o0 = __builtin_amdgcn_mfma_f32_32x32x16_bf16(av0, pf, o0, 0, 0, 0);
          const int row1 = 32 + l31;
          bf16x8 av1 = *(const bf16x8*)(Vsb + row1 * 128 + ((c ^ (row1 & 7)) * 16));
          o1 = __builtin_amdgcn_mfma_f32_32x32x16_bf16(av1, pf, o1, 0, 0, 0);
        }
      }
    }

    // combine l across lane halves (rows 0-15 / 16-31 of the k-tile)
    float la = l_acc, lb = l_acc;
    asm("v_permlane32_swap_b32 %0, %1" : "+v"(la), "+v"(lb));
    const float lt = la + lb;

    // --- epilogue: cross-wk reduction + transposed coalesced store ---
    __syncthreads();   // all chunk-phase LDS reads done; overlay smem

    float* ob = (float*)smem + (wk * 2 + wq) * (64 * 33);
#pragma unroll
    for (int r = 0; r < 16; r++) {
      const int d0 = (r & 3) + 8 * (r >> 2) + 4 * q1;
      ob[d0 * 33 + l31]        = o0[r];
      ob[(32 + d0) * 33 + l31] = o1[r];
    }
    if (lane < 32) LB[wk * 64 + wq * 32 + l31] = lt;
    __syncthreads();

    const int row = tid >> 2;            // 0..63 : output q row within strip
    const int dg  = tid & 3;             // 16-wide d group
    const int wqr = row >> 5, ql = row & 31;
    const float inv = 1.0f / (LB[row] + LB[64 + row]);
    const float* obA = (const float*)smem + (0 * 2 + wqr) * (64 * 33);
    const float* obB = (const float*)smem + (1 * 2 + wqr) * (64 * 33);

    float vout[16];
#pragma unroll
    for (int i = 0; i < 16; i++) {
      const int d = dg * 16 + i;
      vout[i] = (obA[d * 33 + ql] + obB[d * 33 + ql]) * inv;
    }
    const int t = strip * 64 + row;
    float* dst = Out + (size_t)(b * T_SEQ + t) * D_MODEL + h * D_HEAD + dg * 16;
#pragma unroll
    for (int m = 0; m < 4; m++)
      *(float4*)(dst + 4 * m) = *(const float4*)(vout + 4 * m);
  }
}

// ---------------------------------------------------------------------------
extern "C" void kernel_launch(void* const* d_in, const int* in_sizes, int n_in,
                              void* d_out, int out_size, void* d_ws, size_t ws_size,
                              hipStream_t stream) {
  const float* X  = (const float*)d_in[0];
  const float* Wq = (const float*)d_in[1];
  const float* Wk = (const float*)d_in[2];
  const float* Wv = (const float*)d_in[3];

  unsigned short* Qb = (unsigned short*)d_ws;
  unsigned short* Kb = Qb + (size_t)BATCH * N_HEADS * T_SEQ * D_HEAD;
  unsigned short* VT = Kb + (size_t)BATCH * N_HEADS * T_SEQ * D_HEAD;

  unsigned short* Xb = (unsigned short*)d_out;   // scratch, overwritten by attn
  unsigned short* Wb = Xb + (size_t)NX;

  cvt_kernel<<<3584, 256, 0, stream>>>(X, Wq, Wk, Wv, Xb, Wb);

  dim3 g1(N_TOT / 128, M_TOT / 128);
  gemm_qkv<<<g1, 256, 0, stream>>>(Xb, Wb, Qb, Kb, VT);

  attn_kernel<<<512, 256, 0, stream>>>(Qb, Kb, VT, (float*)d_out);
}

// Round 5
// 149.763 us; speedup vs baseline: 1.0315x; 1.0315x over previous
//
#include <hip/hip_runtime.h>

// B=2, T=2048, D_MODEL=1024, H=16, Dh=64. Inputs fp32, output fp32.
// R16: attn stall-structure fix. R15 post-mortem: 33 barrier-iters in 45us =
// ~3300cy/iter vs <=600cy of real work -> vmcnt(0)-drain at each barrier with
// only 2 blocks/CU is the cost. Changes (compute body identical to R15):
//  1) 2-chunk mega-iterations: stage chunk PAIRS (32KB) into 2-deep pair
//     buffers (64KB LDS, still 2 blocks/CU). One barrier+drain per 128 keys
//     instead of 64; staged pair has a full 2-chunk compute (~1200cy) in
//     flight before its drain covers L2 latency (~300cy).
//  2) s_setprio(1) around MFMA clusters (T5, attn +4-7%).
// Geometry unchanged: 64q strips, pairs {p,31-p}, grid 512x256, 2x2 wave
// grid, 32x32x16 MFMA, register P via cvt_pk+permlane32_swap.
// gemm/cvt unchanged.

using bf16x8   = __attribute__((ext_vector_type(8))) __bf16;
using floatx4  = __attribute__((ext_vector_type(4))) float;
using floatx16 = __attribute__((ext_vector_type(16))) float;
using uintx4   = __attribute__((ext_vector_type(4))) unsigned int;

#define T_SEQ   2048
#define D_MODEL 1024
#define N_HEADS 16
#define D_HEAD  64
#define BATCH   2
#define M_TOT   4096
#define N_TOT   3072
#define PLANE   (T_SEQ * D_HEAD)
#define NX      (M_TOT * D_MODEL)
#define NWSEG   (D_MODEL * D_MODEL)
#define QSCALE  0.18033688f   // 0.125 * log2(e)
#define SM_BIAS 24.0f

__device__ __forceinline__ unsigned short f32_to_bf16(float f) {
  unsigned int u = __float_as_uint(f);
  u += 0x7fffu + ((u >> 16) & 1u);
  return (unsigned short)(u >> 16);
}
__device__ __forceinline__ unsigned int pack2_bf16(float a, float b) {
  unsigned int ua = __float_as_uint(a) + 0x8000u;
  unsigned int ub = __float_as_uint(b) + 0x8000u;
  return __builtin_amdgcn_perm(ub, ua, 0x07060302);
}
__device__ __forceinline__ void async_cp16(void* lds, const void* gptr) {
  __builtin_amdgcn_global_load_lds(
      (const __attribute__((address_space(1))) unsigned int*)gptr,
      (__attribute__((address_space(3))) unsigned int*)lds, 16, 0, 0);
}

// ---------------------------------------------------------------------------
// K0: fp32 -> bf16 cvt.
// ---------------------------------------------------------------------------
__global__ __launch_bounds__(256) void cvt_kernel(
    const float* __restrict__ X,  const float* __restrict__ Wq,
    const float* __restrict__ Wk, const float* __restrict__ Wv,
    unsigned short* __restrict__ Xb, unsigned short* __restrict__ Wb)
{
  const size_t i = ((size_t)blockIdx.x * 256 + threadIdx.x) * 8;
  const float* src;
  unsigned short* dst;
  if (i < NX) { src = X + i; dst = Xb + i; }
  else {
    const size_t r = i - NX;
    const int w = (int)(r >> 20);
    const size_t o = r & (NWSEG - 1);
    src = ((w == 0) ? Wq : (w == 1) ? Wk : Wv) + o;
    dst = Wb + r;
  }
  float4 f0 = *(const float4*)src;
  float4 f1 = *(const float4*)(src + 4);
  uint4 out;
  out.x = pack2_bf16(f0.x, f0.y);
  out.y = pack2_bf16(f0.z, f0.w);
  out.z = pack2_bf16(f1.x, f1.y);
  out.w = pack2_bf16(f1.z, f1.w);
  *(uint4*)dst = out;
}

// ---------------------------------------------------------------------------
// K1: bf16 GEMM C[4096x3072] = Xb @ Wb^T. Grid (24,32), block 256. BK=64.
// ---------------------------------------------------------------------------
__global__ __launch_bounds__(256) void gemm_qkv(
    const unsigned short* __restrict__ Xb,
    const unsigned short* __restrict__ Wb,
    unsigned short* __restrict__ Qb,         // [B][H][T][64] * QSCALE
    unsigned short* __restrict__ Kb,         // [B][H][T][64]
    unsigned short* __restrict__ VTb)        // [B][H][64][T]
{
  __shared__ unsigned short Als[128 * 64];
  __shared__ unsigned short Bls[128 * 64];

  const int tid  = threadIdx.x;
  const int lane = tid & 63;
  const int wave = tid >> 6;
  const int l15  = lane & 15;
  const int quad = lane >> 4;
  const int wm   = wave >> 1, wn = wave & 1;

  const int n_blk = blockIdx.x * 128;
  const int m_blk = blockIdx.y * 128;

  const int swz = (((tid >> 3) ^ tid) & 7) * 8;
  const unsigned short* Ag = Xb + (size_t)(m_blk + (tid >> 3)) * D_MODEL + swz;
  const unsigned short* Bg = Wb + (size_t)(n_blk + (tid >> 3)) * D_MODEL + swz;
  char* Alds = (char*)Als + wave * 1024;
  char* Blds = (char*)Bls + wave * 1024;

  floatx4 acc[4][4] = {};

  for (int k0 = 0; k0 < D_MODEL; k0 += 64) {
    __syncthreads();
#pragma unroll
    for (int p = 0; p < 4; p++) {
      async_cp16(Alds + p * 4096, Ag + (size_t)p * 32 * D_MODEL + k0);
      async_cp16(Blds + p * 4096, Bg + (size_t)p * 32 * D_MODEL + k0);
    }
    __syncthreads();

#pragma unroll
    for (int ks = 0; ks < 2; ks++) {
      bf16x8 a[4], b[4];
#pragma unroll
      for (int i = 0; i < 4; i++) {
        const int sa = ((ks * 4 + quad) ^ (l15 & 7)) * 16;
        a[i] = *(const bf16x8*)((char*)Als + (wm * 64 + 16 * i + l15) * 128 + sa);
        b[i] = *(const bf16x8*)((char*)Bls + (wn * 64 + 16 * i + l15) * 128 + sa);
      }
#pragma unroll
      for (int mi = 0; mi < 4; mi++)
#pragma unroll
        for (int ni = 0; ni < 4; ni++)
          acc[mi][ni] = __builtin_amdgcn_mfma_f32_16x16x32_bf16(a[mi], b[ni], acc[mi][ni], 0, 0, 0);
    }
  }

  // epilogue: stage 64x64 C tile in LDS (swizzled), coalesced copy-out
  __syncthreads();
  char* ep = (char*)Als + wave * 8192;
  const int w_sel  = n_blk >> 10;
  const int m_base = m_blk + wm * 64;
  const int n_base = n_blk + wn * 64;
  const int h      = (n_base & 1023) >> 6;
  const float csc  = (w_sel == 0) ? QSCALE : 1.0f;

  if (w_sel < 2) {
#pragma unroll
    for (int mi = 0; mi < 4; mi++)
#pragma unroll
      for (int ni = 0; ni < 4; ni++)
#pragma unroll
        for (int r = 0; r < 4; r++) {
          const int row  = 16 * mi + quad * 4 + r;
          const int colb = (16 * ni + l15) * 2;
          const int phys = ((colb >> 4) ^ (row & 7)) * 16;
          *(unsigned short*)(ep + row * 128 + phys + (colb & 15)) =
              f32_to_bf16(acc[mi][ni][r] * csc);
        }
  } else {
#pragma unroll
    for (int mi = 0; mi < 4; mi++)
#pragma unroll
      for (int ni = 0; ni < 4; ni++)
#pragma unroll
        for (int r = 0; r < 4; r++) {
          const int row  = 16 * ni + l15;
          const int colb = (16 * mi + quad * 4 + r) * 2;
          const int phys = ((colb >> 4) ^ (row & 7)) * 16;
          *(unsigned short*)(ep + row * 128 + phys + (colb & 15)) =
              f32_to_bf16(acc[mi][ni][r]);
        }
  }
  asm volatile("s_waitcnt lgkmcnt(0)" ::: "memory");

#pragma unroll
  for (int pass = 0; pass < 8; pass++) {
    const int row  = pass * 8 + (lane >> 3);
    const int phys = ((lane & 7) ^ (row & 7)) * 16;
    uint4 v = *(const uint4*)(ep + row * 128 + phys);
    if (w_sel < 2) {
      const int m  = m_base + row;
      const int bb = m >> 11;
      const int t  = m & (T_SEQ - 1);
      unsigned short* dst = ((w_sel == 0) ? Qb : Kb) +
          ((size_t)(bb * N_HEADS + h) * T_SEQ + t) * D_HEAD + (lane & 7) * 8;
      *(uint4*)dst = v;
    } else {
      const int bb = m_base >> 11;
      unsigned short* dst = VTb +
          ((size_t)(bb * N_HEADS + h) * D_HEAD + row) * T_SEQ + (m_base & (T_SEQ - 1)) + (lane & 7) * 8;
      *(uint4*)dst = v;
    }
  }
}

// ---------------------------------------------------------------------------
// K2: causal flash attention, fixed-max softmax, 32x32x16 MFMA.
// Grid 512 x 256: bh = blockIdx & 31 (XCD = bh%8), pair = blockIdx >> 5.
// Block = 4 waves in 2x2 grid (wq q-half x wk k-half); strips {pair,31-pair}.
// 2-chunk mega-iterations: one barrier + one vmcnt drain per 128 keys.
// LDS 64KB: K pair-dbuf [2][16KB] @ 0, V pair-dbuf [2][16KB] @ 32768.
// Epilogue overlays smem (34.3KB).
// ---------------------------------------------------------------------------
__global__ __launch_bounds__(256) void attn_kernel(
    const unsigned short* __restrict__ Qb,   // pre-scaled by QSCALE
    const unsigned short* __restrict__ Kb,
    const unsigned short* __restrict__ VTb,
    float* __restrict__ Out)
{
  __shared__ __align__(16) char smem[65536];

  const int tid  = threadIdx.x;
  const int lane = tid & 63;
  const int wave = tid >> 6;
  const int l31  = lane & 31;
  const int q1   = lane >> 5;
  const int wq   = wave & 1;       // q-half
  const int wk   = wave >> 1;      // k-half

  const int bh   = blockIdx.x & 31;          // inner -> XCD affinity (bh % 8)
  const int pair = blockIdx.x >> 5;          // 0..15

  const unsigned short* Qp = Qb  + (size_t)bh * PLANE;
  const unsigned short* Kp = Kb  + (size_t)bh * PLANE;
  const unsigned short* Vp = VTb + (size_t)bh * PLANE;

  const int swz = (((tid >> 3) ^ tid) & 7) * 8;
  const unsigned short* Kg = Kp + (size_t)(tid >> 3) * D_HEAD + swz;
  const unsigned short* Vg = Vp + (size_t)(tid >> 3) * T_SEQ + swz;
  const int b = bh >> 4, h = bh & 15;

  float* const LB = (float*)(smem + 33792);

  // stage one 64-key chunk c into pair-buffer (c>>1)&1, slot c&1
#define STAGE_CHUNK(c)                                                        \
  do {                                                                        \
    char* kd = smem + (((c) >> 1) & 1) * 16384 + ((c) & 1) * 8192;            \
    char* vd = smem + 32768 + (((c) >> 1) & 1) * 16384 + ((c) & 1) * 8192;    \
    _Pragma("unroll")                                                         \
    for (int p = 0; p < 2; p++) {                                             \
      async_cp16(kd + p * 4096 + wave * 1024,                                 \
                 Kg + (size_t)((c) * 64 + p * 32) * D_HEAD);                  \
      async_cp16(vd + p * 4096 + wave * 1024,                                 \
                 Vg + (size_t)(p * 32) * T_SEQ + (c) * 64);                   \
    }                                                                         \
  } while (0)

#pragma unroll 1
  for (int it = 0; it < 2; it++) {
    const int strip = it ? (31 - pair) : pair;
    const int qbase = strip * 64 + wq * 32;
    const int nch   = strip + 1;

    // Q fragments: B-operand, lane = q (l31), elems = d
    bf16x8 aq[4];
#pragma unroll
    for (int kp = 0; kp < 4; kp++)
      aq[kp] = *(const bf16x8*)(Qp + (size_t)(qbase + l31) * D_HEAD + kp * 16 + q1 * 8);

    floatx16 o0 = {}, o1 = {};
    float l_acc = 0.0f;

    // previous strip's epilogue reads must finish before re-staging
    __syncthreads();

    // prologue: stage chunk pair {0,1}
    STAGE_CHUNK(0);
    if (nch > 1) STAGE_CHUNK(1);

#pragma unroll 1
    for (int j2 = 0; j2 < nch; j2 += 2) {
      __syncthreads();
      if (j2 + 2 < nch) STAGE_CHUNK(j2 + 2);
      if (j2 + 3 < nch) STAGE_CHUNK(j2 + 3);

#pragma unroll
      for (int u = 0; u < 2; u++) {
        const int jc = j2 + u;
        if (jc >= nch) break;
        const char* Ksb = smem + ((jc >> 1) & 1) * 16384 + (jc & 1) * 8192;
        const char* Vsb = smem + 32768 + ((jc >> 1) & 1) * 16384 + (jc & 1) * 8192;
        const int kbase = jc * 64 + wk * 32;

        if (kbase <= qbase + 31) {        // wave's k-half not fully masked
          // S^T = K Q^T: rows = k (l31 within half-tile), cols = q
          floatx16 s = {};
          const int krow = wk * 32 + l31;
          __builtin_amdgcn_s_setprio(1);
#pragma unroll
          for (int kp = 0; kp < 4; kp++) {
            const int phys = (((2 * kp + q1) ^ (krow & 7)) * 16);
            bf16x8 ak = *(const bf16x8*)(Ksb + krow * 128 + phys);
            s = __builtin_amdgcn_mfma_f32_32x32x16_bf16(ak, aq[kp], s, 0, 0, 0);
          }
          __builtin_amdgcn_s_setprio(0);

          if (kbase >= qbase) {           // diagonal tile: mask k > q
            const int q = qbase + l31;
#pragma unroll
            for (int r = 0; r < 16; r++) {
              const int kk = kbase + (r & 3) + 8 * (r >> 2) + 4 * q1;
              if (kk > q) s[r] = -INFINITY;
            }
          }

          // fixed-bias softmax: p = exp2(s - SM_BIAS)
          float pv[16];
#pragma unroll
          for (int r = 0; r < 16; r++)
            pv[r] = __builtin_amdgcn_exp2f(s[r] - SM_BIAS);
#pragma unroll
          for (int r = 0; r < 16; r += 4)
            l_acc += (pv[r] + pv[r + 1]) + (pv[r + 2] + pv[r + 3]);

          // pack to bf16 pairs (consecutive k)
          unsigned int w[8];
#pragma unroll
          for (int m = 0; m < 8; m++)
            asm("v_cvt_pk_bf16_f32 %0, %1, %2" : "=v"(w[m]) : "v"(pv[2 * m]), "v"(pv[2 * m + 1]));

          // build PV B-operand fragments via permlane32_swap, then PV
          __builtin_amdgcn_s_setprio(1);
#pragma unroll
          for (int kp = 0; kp < 2; kp++) {
            unsigned int b0 = w[4 * kp],     b2 = w[4 * kp + 2];
            unsigned int b1 = w[4 * kp + 1], b3 = w[4 * kp + 3];
            asm("v_permlane32_swap_b32 %0, %1" : "+v"(b0), "+v"(b2));
            asm("v_permlane32_swap_b32 %0, %1" : "+v"(b1), "+v"(b3));
            uintx4 uu; uu[0] = b0; uu[1] = b1; uu[2] = b2; uu[3] = b3;
            const bf16x8 pf = __builtin_bit_cast(bf16x8, uu);

            const int c = 4 * wk + 2 * kp + q1;   // key 16B-chunk in V rows
            const int row0 = l31;
            bf16x8 av0 = *(const bf16x8*)(Vsb + row0 * 128 + ((c ^ (row0 & 7)) * 16));
            o0 = __builtin_amdgcn_mfma_f32_32x32x16_bf16(av0, pf, o0, 0, 0, 0);
            const int row1 = 32 + l31;
            bf16x8 av1 = *(const bf16x8*)(Vsb + row1 * 128 + ((c ^ (row1 & 7)) * 16));
            o1 = __builtin_amdgcn_mfma_f32_32x32x16_bf16(av1, pf, o1, 0, 0, 0);
          }
          __builtin_amdgcn_s_setprio(0);
        }
      }
    }

    // combine l across lane halves (rows 0-15 / 16-31 of the k-tile)
    float la = l_acc, lb2 = l_acc;
    asm("v_permlane32_swap_b32 %0, %1" : "+v"(la), "+v"(lb2));
    const float lt = la + lb2;

    // --- epilogue: cross-wk reduction + transposed coalesced store ---
    __syncthreads();   // all chunk-phase LDS reads done; overlay smem

    float* ob = (float*)smem + (wk * 2 + wq) * (64 * 33);
#pragma unroll
    for (int r = 0; r < 16; r++) {
      const int d0 = (r & 3) + 8 * (r >> 2) + 4 * q1;
      ob[d0 * 33 + l31]        = o0[r];
      ob[(32 + d0) * 33 + l31] = o1[r];
    }
    if (lane < 32) LB[wk * 64 + wq * 32 + l31] = lt;
    __syncthreads();

    const int row = tid >> 2;            // 0..63 : output q row within strip
    const int dg  = tid & 3;             // 16-wide d group
    const int wqr = row >> 5, ql = row & 31;
    const float inv = 1.0f / (LB[row] + LB[64 + row]);
    const float* obA = (const float*)smem + (0 * 2 + wqr) * (64 * 33);
    const float* obB = (const float*)smem + (1 * 2 + wqr) * (64 * 33);

    float vout[16];
#pragma unroll
    for (int i = 0; i < 16; i++) {
      const int d = dg * 16 + i;
      vout[i] = (obA[d * 33 + ql] + obB[d * 33 + ql]) * inv;
    }
    const int t = strip * 64 + row;
    float* dst = Out + (size_t)(b * T_SEQ + t) * D_MODEL + h * D_HEAD + dg * 16;
#pragma unroll
    for (int m = 0; m < 4; m++)
      *(float4*)(dst + 4 * m) = *(const float4*)(vout + 4 * m);
  }
#undef STAGE_CHUNK
}

// ---------------------------------------------------------------------------
extern "C" void kernel_launch(void* const* d_in, const int* in_sizes, int n_in,
                              void* d_out, int out_size, void* d_ws, size_t ws_size,
                              hipStream_t stream) {
  const float* X  = (const float*)d_in[0];
  const float* Wq = (const float*)d_in[1];
  const float* Wk = (const float*)d_in[2];
  const float* Wv = (const float*)d_in[3];

  unsigned short* Qb = (unsigned short*)d_ws;
  unsigned short* Kb = Qb + (size_t)BATCH * N_HEADS * T_SEQ * D_HEAD;
  unsigned short* VT = Kb + (size_t)BATCH * N_HEADS * T_SEQ * D_HEAD;

  unsigned short* Xb = (unsigned short*)d_out;   // scratch, overwritten by attn
  unsigned short* Wb = Xb + (size_t)NX;

  cvt_kernel<<<3584, 256, 0, stream>>>(X, Wq, Wk, Wv, Xb, Wb);

  dim3 g1(N_TOT / 128, M_TOT / 128);
  gemm_qkv<<<g1, 256, 0, stream>>>(Xb, Wb, Qb, Kb, VT);

  attn_kernel<<<512, 256, 0, stream>>>(Qb, Kb, VT, (float*)d_out);
}